// Round 1
// baseline (2683.329 us; speedup 1.0000x reference)
//
#include <hip/hip_runtime.h>

// Sizes (hard-coded from setup_inputs):
//   B=2048, D_IN=1024, T=64, H1=H2=D_OUT=512
constexpr int TN = 64;

// Fused GEMM + LIF scan.
//   grid (2, B), block 256.
//   Block computes C[h0..h0+255][0..63] = W[h0..][:] @ X_b[:][t] (+bias in epilogue),
//   then scans membrane dynamics over t.
// PIN=false: input = float spikes [B][KDIM][64]; output = packed spike bits u64 [B][512]
// PIN=true : input = packed spike bits u64 [B][KDIM]; output = acc f32 [B][512]
template <int KDIM, bool PIN>
__global__ __launch_bounds__(256) void gemm_scan(
    const float* __restrict__ Xf,
    const unsigned long long* __restrict__ Xp,
    const float* __restrict__ W,      // [512][KDIM]
    const float* __restrict__ bias,   // [512]
    unsigned long long* __restrict__ Sout,  // [B][512]  (PIN=false)
    float* __restrict__ AccOut)             // [B][512]  (PIN=true)
{
    __shared__ union {
        struct {
            float Wt[32 * 260];  // [kk][row] transposed W chunk, padded stride 260
            float Xc[32 * 64];   // [kk][t]
        } s;
        float C[256 * 64];       // output tile for the scan phase
    } lds;

    const int b   = blockIdx.y;
    const int h0  = blockIdx.x * 256;
    const int tid = threadIdx.x;
    const int tc  = tid & 3;    // t-quarter
    const int tr  = tid >> 2;   // row group
    const int t0  = tc * 16;
    const int r0  = tr * 4;

    float c[4][16];
#pragma unroll
    for (int i = 0; i < 4; ++i)
#pragma unroll
        for (int j = 0; j < 16; ++j) c[i][j] = 0.f;

    for (int k0 = 0; k0 < KDIM; k0 += 32) {
        // ---- stage input chunk [32 k][64 t] into Xc ----
        if constexpr (!PIN) {
            // contiguous: rows k are contiguous 64-float runs
            const float4* xsrc = (const float4*)(Xf + ((size_t)b * KDIM + k0) * 64);
            float4* xdst = (float4*)lds.s.Xc;
            xdst[tid]       = xsrc[tid];
            xdst[tid + 256] = xsrc[tid + 256];
        } else {
            // unpack spike bits: row = k index, bit t
            const int row  = tid >> 3;
            const int bofs = (tid & 7) * 8;
            unsigned long long m = Xp[(size_t)b * KDIM + k0 + row];
            float* xd = &lds.s.Xc[row * 64 + bofs];
#pragma unroll
            for (int q = 0; q < 8; ++q)
                xd[q] = (float)((m >> (bofs + q)) & 1ull);
        }
        // ---- stage W chunk transposed: Wt[kk][row], rows h0..h0+255 ----
#pragma unroll
        for (int i = 0; i < 8; ++i) {
            int g = tid + 256 * i;
            int row = g >> 3, c4 = g & 7;
            float4 w4 = *(const float4*)(W + (size_t)(h0 + row) * KDIM + k0 + c4 * 4);
            lds.s.Wt[(c4 * 4 + 0) * 260 + row] = w4.x;
            lds.s.Wt[(c4 * 4 + 1) * 260 + row] = w4.y;
            lds.s.Wt[(c4 * 4 + 2) * 260 + row] = w4.z;
            lds.s.Wt[(c4 * 4 + 3) * 260 + row] = w4.w;
        }
        __syncthreads();
#pragma unroll 4
        for (int kk = 0; kk < 32; ++kk) {
            float4 wv = *(const float4*)&lds.s.Wt[kk * 260 + r0];
            const float4* xr = (const float4*)&lds.s.Xc[kk * 64 + t0];
            float4 x0 = xr[0], x1 = xr[1], x2 = xr[2], x3 = xr[3];
            float wr[4]  = {wv.x, wv.y, wv.z, wv.w};
            float xs[16] = {x0.x, x0.y, x0.z, x0.w, x1.x, x1.y, x1.z, x1.w,
                            x2.x, x2.y, x2.z, x2.w, x3.x, x3.y, x3.z, x3.w};
#pragma unroll
            for (int i = 0; i < 4; ++i)
#pragma unroll
                for (int j = 0; j < 16; ++j)
                    c[i][j] = fmaf(wr[i], xs[j], c[i][j]);
        }
        __syncthreads();
    }

    // ---- park C tile in LDS so each thread can own one full row for the scan ----
#pragma unroll
    for (int i = 0; i < 4; ++i)
#pragma unroll
        for (int j4 = 0; j4 < 4; ++j4)
            *(float4*)&lds.C[(r0 + i) * 64 + t0 + j4 * 4] =
                make_float4(c[i][j4 * 4], c[i][j4 * 4 + 1], c[i][j4 * 4 + 2], c[i][j4 * 4 + 3]);
    __syncthreads();

    // ---- LIF scan over t (thread owns row h0+tid) ----
    const float bb = bias[h0 + tid];
    float v = 0.f, s = 0.f;
    if constexpr (!PIN) {
        unsigned long long m = 0;
#pragma unroll
        for (int t = 0; t < TN; ++t) {
            float cc = lds.C[tid * 64 + t] + bb;
            v = v * (1.f - s) * 0.75f + cc;   // prev-step s
            bool sp = v > 0.5f;
            s = sp ? 1.f : 0.f;
            if (sp) m |= (1ull << t);
        }
        Sout[(size_t)b * 512 + h0 + tid] = m;
    } else {
        float acc = 0.f;
#pragma unroll
        for (int t = 0; t < TN; ++t) {
            float cc = lds.C[tid * 64 + t] + bb;
            v = v * (1.f - s) * 0.75f + cc;
            bool sp = v > 0.5f;
            s = sp ? 1.f : 0.f;
            acc += s;
        }
        AccOut[(size_t)b * 512 + h0 + tid] = acc;
    }
}

// out[2048][512] = ACC[2048][512] @ Wout[512][512]^T + bout
// grid (512/64, 2048/64) = (8, 32), block 256, thread tile 4x4, KC=32
__global__ __launch_bounds__(256) void k3_gemm(
    const float* __restrict__ A,   // [2048][512]
    const float* __restrict__ Wo,  // [512][512]
    const float* __restrict__ bq,  // [512]
    float* __restrict__ C)         // [2048][512]
{
    __shared__ float Al[64][33];
    __shared__ float Bl[32][65];
    const int n0 = blockIdx.x * 64;
    const int m0 = blockIdx.y * 64;
    const int tid = threadIdx.x;
    const int c0 = (tid & 15) * 4;
    const int r0 = (tid >> 4) * 4;
    float acc[4][4];
#pragma unroll
    for (int i = 0; i < 4; ++i)
#pragma unroll
        for (int j = 0; j < 4; ++j) acc[i][j] = 0.f;

    for (int k0 = 0; k0 < 512; k0 += 32) {
#pragma unroll
        for (int i = 0; i < 2; ++i) {
            int g = tid + 256 * i;
            int row = g >> 3, c4 = g & 7;
            float4 v = *(const float4*)(A + (size_t)(m0 + row) * 512 + k0 + c4 * 4);
            float* d = &Al[row][c4 * 4];
            d[0] = v.x; d[1] = v.y; d[2] = v.z; d[3] = v.w;
        }
#pragma unroll
        for (int i = 0; i < 2; ++i) {
            int g = tid + 256 * i;
            int row = g >> 3, c4 = g & 7;
            float4 v = *(const float4*)(Wo + (size_t)(n0 + row) * 512 + k0 + c4 * 4);
            Bl[c4 * 4 + 0][row] = v.x;
            Bl[c4 * 4 + 1][row] = v.y;
            Bl[c4 * 4 + 2][row] = v.z;
            Bl[c4 * 4 + 3][row] = v.w;
        }
        __syncthreads();
#pragma unroll 8
        for (int kk = 0; kk < 32; ++kk) {
            float a0 = Al[r0 + 0][kk], a1 = Al[r0 + 1][kk];
            float a2 = Al[r0 + 2][kk], a3 = Al[r0 + 3][kk];
            float b0 = Bl[kk][c0 + 0], b1 = Bl[kk][c0 + 1];
            float b2 = Bl[kk][c0 + 2], b3 = Bl[kk][c0 + 3];
            acc[0][0] = fmaf(a0, b0, acc[0][0]); acc[0][1] = fmaf(a0, b1, acc[0][1]);
            acc[0][2] = fmaf(a0, b2, acc[0][2]); acc[0][3] = fmaf(a0, b3, acc[0][3]);
            acc[1][0] = fmaf(a1, b0, acc[1][0]); acc[1][1] = fmaf(a1, b1, acc[1][1]);
            acc[1][2] = fmaf(a1, b2, acc[1][2]); acc[1][3] = fmaf(a1, b3, acc[1][3]);
            acc[2][0] = fmaf(a2, b0, acc[2][0]); acc[2][1] = fmaf(a2, b1, acc[2][1]);
            acc[2][2] = fmaf(a2, b2, acc[2][2]); acc[2][3] = fmaf(a2, b3, acc[2][3]);
            acc[3][0] = fmaf(a3, b0, acc[3][0]); acc[3][1] = fmaf(a3, b1, acc[3][1]);
            acc[3][2] = fmaf(a3, b2, acc[3][2]); acc[3][3] = fmaf(a3, b3, acc[3][3]);
        }
        __syncthreads();
    }
#pragma unroll
    for (int i = 0; i < 4; ++i) {
        float4 o = make_float4(acc[i][0] + bq[n0 + c0 + 0],
                               acc[i][1] + bq[n0 + c0 + 1],
                               acc[i][2] + bq[n0 + c0 + 2],
                               acc[i][3] + bq[n0 + c0 + 3]);
        *(float4*)&C[(size_t)(m0 + r0 + i) * 512 + n0 + c0] = o;
    }
}

extern "C" void kernel_launch(void* const* d_in, const int* in_sizes, int n_in,
                              void* d_out, int out_size, void* d_ws, size_t ws_size,
                              hipStream_t stream) {
    const float* X  = (const float*)d_in[0];  // [2048][1024][64]
    const float* W1 = (const float*)d_in[1];  // [512][1024]
    const float* b1 = (const float*)d_in[2];  // [512]
    const float* W2 = (const float*)d_in[3];  // [512][512]
    const float* b2 = (const float*)d_in[4];  // [512]
    const float* Wo = (const float*)d_in[5];  // [512][512]
    const float* bo = (const float*)d_in[6];  // [512]
    float* out = (float*)d_out;               // [2048][512]

    // workspace: S1 packed spikes u64 [2048][512] (8 MB), ACC f32 [2048][512] (4 MB)
    unsigned long long* S1 = (unsigned long long*)d_ws;
    float* ACC = (float*)((char*)d_ws + (size_t)2048 * 512 * 8);

    gemm_scan<1024, false><<<dim3(2, 2048), 256, 0, stream>>>(X, nullptr, W1, b1, S1, nullptr);
    gemm_scan<512, true><<<dim3(2, 2048), 256, 0, stream>>>(nullptr, S1, W2, b2, nullptr, ACC);
    k3_gemm<<<dim3(8, 32), 256, 0, stream>>>(ACC, Wo, bo, out);
}

// Round 3
// 571.796 us; speedup vs baseline: 4.6928x; 4.6928x over previous
//
#include <hip/hip_runtime.h>
#include <hip/hip_bf16.h>

typedef __bf16 bf16x8 __attribute__((ext_vector_type(8)));
typedef float f32x4 __attribute__((ext_vector_type(4)));
typedef unsigned int uint;
typedef unsigned long long u64;

constexpr int TN = 64;

// ---------------- ws layout (new path, 27 MB) ----------------
// [0,16M)   XPk1: k-packed input bits  [2048 b][64 t][16 kw] u64
//           (aliased by ACC f32 [2048][512] = 4MB once K1 is done)
// [16M,24M) XP2 : k-packed s1 bits     [2048 b][64 t][8 kw] u64
// [24M,25M) W1hi pack  [4 hb][16 kb][128][64] bf16 swizzled
// [25M,26M) W1lo pack
// [26M,26.5M) W2hi pack [4 hb][8 kb][128][64]
// [26.5M,27M) W2lo pack
static constexpr size_t OFF_XP2  = (size_t)16 << 20;
static constexpr size_t OFF_W1HI = (size_t)24 << 20;
static constexpr size_t OFF_W1LO = (size_t)25 << 20;
static constexpr size_t OFF_W2HI = (size_t)26 << 20;
static constexpr size_t OFF_W2LO = ((size_t)26 << 20) + ((size_t)512 << 10);
static constexpr size_t WS_NEED  = (size_t)27 << 20;

// ---------------- P0: bit-transpose-pack X ----------------
// X [2048 b][1024 k][64 t] f32 (binary) -> XPk1[b][t][kw] u64, bit j = x[b][kw*64+j][t]
__global__ __launch_bounds__(256) void pack_x(const float* __restrict__ X,
                                              u64* __restrict__ XP) {
    __shared__ float L[64 * 65];
    const int kw = blockIdx.x;   // 0..15
    const int b  = blockIdx.y;   // 0..2047
    const int tid = threadIdx.x;
    const float* src = X + (((size_t)b * 1024 + kw * 64) << 6);
#pragma unroll
    for (int i = 0; i < 4; ++i) {
        int flat = tid + i * 256;          // float4 index
        float4 v = ((const float4*)src)[flat];
        int e0 = flat * 4;
        int k = e0 >> 6, t0 = e0 & 63;
        float* d = &L[k * 65 + t0];
        d[0] = v.x; d[1] = v.y; d[2] = v.z; d[3] = v.w;
    }
    __syncthreads();
    const int w = tid >> 6, lane = tid & 63;
    u64 myw = 0;
#pragma unroll
    for (int tt = 0; tt < 16; ++tt) {
        int t = w * 16 + tt;
        bool pred = L[lane * 65 + t] > 0.5f;
        u64 bm = __ballot(pred);
        if (lane == tt) myw = bm;
    }
    if (lane < 16) XP[((size_t)b * 64 + w * 16 + lane) * 16 + kw] = myw;
}

// ---------------- P1: split W into hi/lo bf16, packed + swizzled ----------------
// W [H][K] f32 -> hi/lo [H/128 hb][K/64 kb][128 row][64 k] bf16,
// byte-in-tile = (row*128 + k*2) ^ ((row&7)<<4)
__global__ __launch_bounds__(256) void pack_w(const float* __restrict__ W, int kshift, int KB,
                                              unsigned short* __restrict__ hiP,
                                              unsigned short* __restrict__ loP) {
    int g = blockIdx.x * 256 + threadIdx.x;
    int h = g >> kshift;
    int k = g & ((1 << kshift) - 1);
    float v = W[g];
    __hip_bfloat16 hb16 = __float2bfloat16(v);
    float hf = __bfloat162float(hb16);
    __hip_bfloat16 lb16 = __float2bfloat16(v - hf);
    int tile = (h >> 7) * KB + (k >> 6);
    int row = h & 127, kc = k & 63;
    int byte = (row * 128 + kc * 2) ^ ((row & 7) << 4);
    size_t idx = ((size_t)tile << 13) + (byte >> 1);
    hiP[idx] = __hip_bfloat16_raw(hb16).x;
    loP[idx] = __hip_bfloat16_raw(lb16).x;
}

// ---------------- main fused MFMA GEMM + LIF scan ----------------
// C[h][n] = (Whi+Wlo)[h][:] dot Xbits[:][n],  n = b*64 + t, per-block tile 128h x 128n.
// KB = K/64.  EMIT: epilogue emits spike bits (layer 1).  !EMIT: emits acc sum (layer 2).
template <int KB, bool EMIT>
__global__ __launch_bounds__(256) void spike_mfma(
    const unsigned short* __restrict__ WhiP, const unsigned short* __restrict__ WloP,
    const u64* __restrict__ XPsrc,    // [b][t][KB]
    const float* __restrict__ bias,   // [512]
    u64* __restrict__ XPdst,          // EMIT: [b][t][8]
    float* __restrict__ AccOut)       // !EMIT: [b][512]
{
    __shared__ __align__(16) char smem[65536];
    // GEMM phase: Ahi [0,16K), Alo [16K,32K), B^T [32K,48K). Epilogue: C [0,64K).
    const int tid = threadIdx.x;
    const int nb = blockIdx.x;           // 0..1023
    const int hb = blockIdx.y;           // 0..3
    const int b0 = nb * 2;
    const int w = tid >> 6, lane = tid & 63;
    const int wm = w >> 1, wn = w & 1;

    f32x4 acc[4][4] = {};

    // B-unpack assignment: thread -> (row n, 32-bit half)
    const int un = tid >> 1;
    const int uhalf = tid & 1;
    const int ub = b0 + (un >> 6), ut = un & 63;
    const u64* usrc = XPsrc + ((size_t)ub * 64 + ut) * KB;
    char* ldsB = smem + 32768;

    const uint4* ghBase = (const uint4*)(WhiP + ((size_t)hb * KB) * 8192);
    const uint4* glBase = (const uint4*)(WloP + ((size_t)hb * KB) * 8192);

    const int lrow = lane & 15;
    const int lk16 = (lane >> 4) * 16;

    for (int kb = 0; kb < KB; ++kb) {
        __syncthreads();
        // ---- stage A (linear copy of pre-swizzled tiles; tile = 1024 uint4) ----
        const uint4* gh = ghBase + kb * 1024;
        const uint4* gl = glBase + kb * 1024;
        uint4 ra[4], rl[4];
#pragma unroll
        for (int r = 0; r < 4; ++r) ra[r] = gh[tid + r * 256];
#pragma unroll
        for (int r = 0; r < 4; ++r) rl[r] = gl[tid + r * 256];
        // ---- unpack B bits -> bf16 ----
        u64 wbits = usrc[kb];
        uint bits = (uint)(wbits >> (uhalf * 32));
        uint outw[16];
#pragma unroll
        for (int j = 0; j < 16; ++j)
            outw[j] = (((bits >> (2 * j)) & 1u) ? 0x3f80u : 0u) |
                      (((bits >> (2 * j + 1)) & 1u) ? 0x3f800000u : 0u);
#pragma unroll
        for (int r = 0; r < 4; ++r) *(uint4*)(smem + tid * 16 + r * 4096) = ra[r];
#pragma unroll
        for (int r = 0; r < 4; ++r) *(uint4*)(smem + 16384 + tid * 16 + r * 4096) = rl[r];
        const uint bbase = un * 128 + uhalf * 64;
#pragma unroll
        for (int q = 0; q < 4; ++q) {
            uint4 o; o.x = outw[q * 4]; o.y = outw[q * 4 + 1];
            o.z = outw[q * 4 + 2]; o.w = outw[q * 4 + 3];
            *(uint4*)(ldsB + ((bbase + q * 16) ^ ((un & 7) << 4))) = o;
        }
        __syncthreads();
        // ---- MFMA ----
#pragma unroll
        for (int kk = 0; kk < 2; ++kk) {
            const int koff = kk * 64 + lk16;
            bf16x8 ah[4], al[4], bv[4];
#pragma unroll
            for (int mi = 0; mi < 4; ++mi) {
                int row = wm * 64 + mi * 16 + lrow;
                int byte = (row * 128 + koff) ^ ((row & 7) << 4);
                ah[mi] = __builtin_bit_cast(bf16x8, *(const uint4*)(smem + byte));
                al[mi] = __builtin_bit_cast(bf16x8, *(const uint4*)(smem + 16384 + byte));
            }
#pragma unroll
            for (int ni = 0; ni < 4; ++ni) {
                int row = wn * 64 + ni * 16 + lrow;
                int byte = (row * 128 + koff) ^ ((row & 7) << 4);
                bv[ni] = __builtin_bit_cast(bf16x8, *(const uint4*)(ldsB + byte));
            }
#pragma unroll
            for (int mi = 0; mi < 4; ++mi)
#pragma unroll
                for (int ni = 0; ni < 4; ++ni) {
                    acc[mi][ni] = __builtin_amdgcn_mfma_f32_16x16x32_bf16(ah[mi], bv[ni], acc[mi][ni], 0, 0, 0);
                    acc[mi][ni] = __builtin_amdgcn_mfma_f32_16x16x32_bf16(al[mi], bv[ni], acc[mi][ni], 0, 0, 0);
                }
        }
    }
    __syncthreads();
    // ---- park C tile per wave as [t][h], 16B-granule XOR swizzle ----
    char* Cs = smem + w * 16384;
#pragma unroll
    for (int mi = 0; mi < 4; ++mi) {
        int hl0 = mi * 16 + (lane >> 4) * 4;
#pragma unroll
        for (int ni = 0; ni < 4; ++ni) {
            int t = ni * 16 + (lane & 15);
            *(f32x4*)(Cs + t * 256 + ((hl0 * 4) ^ ((t & 15) << 4))) = acc[mi][ni];
        }
    }
    asm volatile("s_waitcnt lgkmcnt(0)" ::: "memory");
    // ---- LIF scan over t; lane owns h-row = lane within wave tile ----
    const int hq = hb * 128 + wm * 64 + lane;
    const float bv2 = bias[hq];
    const int bq = b0 + wn;
    float v = 0.f, s = 0.f;
    if constexpr (EMIT) {
        u64 myw = 0;
        for (int t = 0; t < TN; ++t) {
            float cc = *(const float*)(Cs + t * 256 + ((lane * 4) ^ ((t & 15) << 4))) + bv2;
            v = v * (1.f - s) * 0.75f + cc;
            bool sp = v > 0.5f;
            s = sp ? 1.f : 0.f;
            u64 bm = __ballot(sp);
            if (lane == t) myw = bm;
        }
        XPdst[((size_t)bq * 64 + lane) * 8 + (hb * 2 + wm)] = myw;
    } else {
        float a = 0.f;
        for (int t = 0; t < TN; ++t) {
            float cc = *(const float*)(Cs + t * 256 + ((lane * 4) ^ ((t & 15) << 4))) + bv2;
            v = v * (1.f - s) * 0.75f + cc;
            bool sp = v > 0.5f;
            s = sp ? 1.f : 0.f;
            a += s;
        }
        AccOut[(size_t)bq * 512 + hq] = a;
    }
}

// ---------------- K3: out = ACC @ Wout^T + bout (f32 VALU) ----------------
__global__ __launch_bounds__(256) void k3_gemm(
    const float* __restrict__ A, const float* __restrict__ Wo,
    const float* __restrict__ bq, float* __restrict__ C) {
    __shared__ float Al[64][33];
    __shared__ float Bl[32][65];
    const int n0 = blockIdx.x * 64;
    const int m0 = blockIdx.y * 64;
    const int tid = threadIdx.x;
    const int c0 = (tid & 15) * 4;
    const int r0 = (tid >> 4) * 4;
    float acc[4][4];
#pragma unroll
    for (int i = 0; i < 4; ++i)
#pragma unroll
        for (int j = 0; j < 4; ++j) acc[i][j] = 0.f;
    for (int k0 = 0; k0 < 512; k0 += 32) {
#pragma unroll
        for (int i = 0; i < 2; ++i) {
            int g = tid + 256 * i;
            int row = g >> 3, c4 = g & 7;
            float4 v = *(const float4*)(A + (size_t)(m0 + row) * 512 + k0 + c4 * 4);
            float* d = &Al[row][c4 * 4];
            d[0] = v.x; d[1] = v.y; d[2] = v.z; d[3] = v.w;
        }
#pragma unroll
        for (int i = 0; i < 2; ++i) {
            int g = tid + 256 * i;
            int row = g >> 3, c4 = g & 7;
            float4 v = *(const float4*)(Wo + (size_t)(n0 + row) * 512 + k0 + c4 * 4);
            Bl[c4 * 4 + 0][row] = v.x; Bl[c4 * 4 + 1][row] = v.y;
            Bl[c4 * 4 + 2][row] = v.z; Bl[c4 * 4 + 3][row] = v.w;
        }
        __syncthreads();
#pragma unroll 8
        for (int kk = 0; kk < 32; ++kk) {
            float a0 = Al[r0 + 0][kk], a1 = Al[r0 + 1][kk];
            float a2 = Al[r0 + 2][kk], a3 = Al[r0 + 3][kk];
            float b0 = Bl[kk][c0 + 0], b1 = Bl[kk][c0 + 1];
            float b2 = Bl[kk][c0 + 2], b3 = Bl[kk][c0 + 3];
            acc[0][0] = fmaf(a0, b0, acc[0][0]); acc[0][1] = fmaf(a0, b1, acc[0][1]);
            acc[0][2] = fmaf(a0, b2, acc[0][2]); acc[0][3] = fmaf(a0, b3, acc[0][3]);
            acc[1][0] = fmaf(a1, b0, acc[1][0]); acc[1][1] = fmaf(a1, b1, acc[1][1]);
            acc[1][2] = fmaf(a1, b2, acc[1][2]); acc[1][3] = fmaf(a1, b3, acc[1][3]);
            acc[2][0] = fmaf(a2, b0, acc[2][0]); acc[2][1] = fmaf(a2, b1, acc[2][1]);
            acc[2][2] = fmaf(a2, b2, acc[2][2]); acc[2][3] = fmaf(a2, b3, acc[2][3]);
            acc[3][0] = fmaf(a3, b0, acc[3][0]); acc[3][1] = fmaf(a3, b1, acc[3][1]);
            acc[3][2] = fmaf(a3, b2, acc[3][2]); acc[3][3] = fmaf(a3, b3, acc[3][3]);
        }
        __syncthreads();
    }
#pragma unroll
    for (int i = 0; i < 4; ++i) {
        float4 o = make_float4(acc[i][0] + bq[n0 + c0 + 0], acc[i][1] + bq[n0 + c0 + 1],
                               acc[i][2] + bq[n0 + c0 + 2], acc[i][3] + bq[n0 + c0 + 3]);
        *(float4*)&C[(size_t)(m0 + r0 + i) * 512 + n0 + c0] = o;
    }
}

// ---------------- fallback f32 path (ws too small) ----------------
template <int KDIM, bool PIN>
__global__ __launch_bounds__(256) void gemm_scan(
    const float* __restrict__ Xf, const u64* __restrict__ Xp,
    const float* __restrict__ W, const float* __restrict__ bias,
    u64* __restrict__ Sout, float* __restrict__ AccOut) {
    __shared__ union {
        struct { float Wt[32 * 260]; float Xc[32 * 64]; } s;
        float C[256 * 64];
    } lds;
    const int b = blockIdx.y;
    const int h0 = blockIdx.x * 256;
    const int tid = threadIdx.x;
    const int tc = tid & 3, tr = tid >> 2;
    const int t0 = tc * 16, r0 = tr * 4;
    float c[4][16];
#pragma unroll
    for (int i = 0; i < 4; ++i)
#pragma unroll
        for (int j = 0; j < 16; ++j) c[i][j] = 0.f;
    for (int k0 = 0; k0 < KDIM; k0 += 32) {
        if constexpr (!PIN) {
            const float4* xsrc = (const float4*)(Xf + ((size_t)b * KDIM + k0) * 64);
            float4* xdst = (float4*)lds.s.Xc;
            xdst[tid] = xsrc[tid];
            xdst[tid + 256] = xsrc[tid + 256];
        } else {
            const int row = tid >> 3;
            const int bofs = (tid & 7) * 8;
            u64 m = Xp[(size_t)b * KDIM + k0 + row];
            float* xd = &lds.s.Xc[row * 64 + bofs];
#pragma unroll
            for (int q = 0; q < 8; ++q) xd[q] = (float)((m >> (bofs + q)) & 1ull);
        }
#pragma unroll
        for (int i = 0; i < 8; ++i) {
            int g = tid + 256 * i;
            int row = g >> 3, c4 = g & 7;
            float4 w4 = *(const float4*)(W + (size_t)(h0 + row) * KDIM + k0 + c4 * 4);
            lds.s.Wt[(c4 * 4 + 0) * 260 + row] = w4.x;
            lds.s.Wt[(c4 * 4 + 1) * 260 + row] = w4.y;
            lds.s.Wt[(c4 * 4 + 2) * 260 + row] = w4.z;
            lds.s.Wt[(c4 * 4 + 3) * 260 + row] = w4.w;
        }
        __syncthreads();
#pragma unroll 4
        for (int kk = 0; kk < 32; ++kk) {
            float4 wv = *(const float4*)&lds.s.Wt[kk * 260 + r0];
            const float4* xr = (const float4*)&lds.s.Xc[kk * 64 + t0];
            float4 x0 = xr[0], x1 = xr[1], x2 = xr[2], x3 = xr[3];
            float wr[4] = {wv.x, wv.y, wv.z, wv.w};
            float xs[16] = {x0.x, x0.y, x0.z, x0.w, x1.x, x1.y, x1.z, x1.w,
                            x2.x, x2.y, x2.z, x2.w, x3.x, x3.y, x3.z, x3.w};
#pragma unroll
            for (int i = 0; i < 4; ++i)
#pragma unroll
                for (int j = 0; j < 16; ++j) c[i][j] = fmaf(wr[i], xs[j], c[i][j]);
        }
        __syncthreads();
    }
#pragma unroll
    for (int i = 0; i < 4; ++i)
#pragma unroll
        for (int j4 = 0; j4 < 4; ++j4)
            *(float4*)&lds.C[(r0 + i) * 64 + t0 + j4 * 4] =
                make_float4(c[i][j4 * 4], c[i][j4 * 4 + 1], c[i][j4 * 4 + 2], c[i][j4 * 4 + 3]);
    __syncthreads();
    const float bb = bias[h0 + tid];
    float v = 0.f, s = 0.f;
    if constexpr (!PIN) {
        u64 m = 0;
#pragma unroll
        for (int t = 0; t < TN; ++t) {
            float cc = lds.C[tid * 64 + t] + bb;
            v = v * (1.f - s) * 0.75f + cc;
            bool sp = v > 0.5f;
            s = sp ? 1.f : 0.f;
            if (sp) m |= (1ull << t);
        }
        Sout[(size_t)b * 512 + h0 + tid] = m;
    } else {
        float acc = 0.f;
#pragma unroll
        for (int t = 0; t < TN; ++t) {
            float cc = lds.C[tid * 64 + t] + bb;
            v = v * (1.f - s) * 0.75f + cc;
            bool sp = v > 0.5f;
            s = sp ? 1.f : 0.f;
            acc += s;
        }
        AccOut[(size_t)b * 512 + h0 + tid] = acc;
    }
}

extern "C" void kernel_launch(void* const* d_in, const int* in_sizes, int n_in,
                              void* d_out, int out_size, void* d_ws, size_t ws_size,
                              hipStream_t stream) {
    const float* X  = (const float*)d_in[0];
    const float* W1 = (const float*)d_in[1];
    const float* b1 = (const float*)d_in[2];
    const float* W2 = (const float*)d_in[3];
    const float* b2 = (const float*)d_in[4];
    const float* Wo = (const float*)d_in[5];
    const float* bo = (const float*)d_in[6];
    float* out = (float*)d_out;

    if (ws_size >= WS_NEED) {
        char* ws = (char*)d_ws;
        u64* XPk1 = (u64*)ws;
        u64* XP2  = (u64*)(ws + OFF_XP2);
        unsigned short* W1hi = (unsigned short*)(ws + OFF_W1HI);
        unsigned short* W1lo = (unsigned short*)(ws + OFF_W1LO);
        unsigned short* W2hi = (unsigned short*)(ws + OFF_W2HI);
        unsigned short* W2lo = (unsigned short*)(ws + OFF_W2LO);
        float* ACC = (float*)ws;  // aliases XPk1 (dead after K1)

        pack_x<<<dim3(16, 2048), 256, 0, stream>>>(X, XPk1);
        pack_w<<<dim3(2048), 256, 0, stream>>>(W1, 10, 16, W1hi, W1lo);
        pack_w<<<dim3(1024), 256, 0, stream>>>(W2, 9, 8, W2hi, W2lo);
        spike_mfma<16, true><<<dim3(1024, 4), 256, 0, stream>>>(W1hi, W1lo, XPk1, b1, XP2, nullptr);
        spike_mfma<8, false><<<dim3(1024, 4), 256, 0, stream>>>(W2hi, W2lo, XP2, b2, nullptr, ACC);
        k3_gemm<<<dim3(8, 32), 256, 0, stream>>>(ACC, Wo, bo, out);
    } else {
        // fallback: f32 VALU path (needs 12 MB)
        u64* S1 = (u64*)d_ws;
        float* ACC = (float*)((char*)d_ws + (size_t)2048 * 512 * 8);
        gemm_scan<1024, false><<<dim3(2, 2048), 256, 0, stream>>>(X, nullptr, W1, b1, S1, nullptr);
        gemm_scan<512, true><<<dim3(2, 2048), 256, 0, stream>>>(nullptr, S1, W2, b2, nullptr, ACC);
        k3_gemm<<<dim3(8, 32), 256, 0, stream>>>(ACC, Wo, bo, out);
    }
}